// Round 1
// baseline (11641.610 us; speedup 1.0000x reference)
//
#include <hip/hip_runtime.h>

#define BB   512
#define SS   256
#define NIN  128
#define DH   1024
#define DC   1152   // NIN + DH
#define NOUT 128
#define EPSV 1e-5f

typedef _Float16 f16;
typedef _Float16 f16x8 __attribute__((ext_vector_type(8)));
typedef _Float16 f16x4 __attribute__((ext_vector_type(4)));
typedef float    f32x4 __attribute__((ext_vector_type(4)));

__device__ __forceinline__ float sigmoid_(float x) { return 1.0f / (1.0f + __expf(-x)); }
__device__ __forceinline__ float tanh_(float x) {
    x = fminf(fmaxf(x, -15.0f), 15.0f);
    float e = __expf(2.0f * x);
    return (e - 1.0f) / (e + 1.0f);
}

// ---------------- weight conversion (fp32 -> fp16), runs once per launch ----------------
__global__ void k_convert(const float* __restrict__ Wu, const float* __restrict__ Wr,
                          const float* __restrict__ Wh_, const float* __restrict__ Wo_,
                          f16* __restrict__ wur, f16* __restrict__ wh, f16* __restrict__ wo)
{
    const int stride = gridDim.x * blockDim.x;
    const int i0 = blockIdx.x * blockDim.x + threadIdx.x;
    // wur: [2048][1152] = rows 0..1023 -> W_u, rows 1024..2047 -> W_r
    for (int i = i0; i < 2048 * 1152 / 4; i += stride) {
        int base = i * 4;
        int n = base / 1152, k = base % 1152;
        const float* src = (n < 1024) ? (Wu + (size_t)n * 1152 + k) : (Wr + (size_t)(n - 1024) * 1152 + k);
        float4 v = *(const float4*)src;
        f16x4 o; o[0] = (f16)v.x; o[1] = (f16)v.y; o[2] = (f16)v.z; o[3] = (f16)v.w;
        *(f16x4*)(wur + base) = o;
    }
    for (int i = i0; i < 1024 * 1152 / 4; i += stride) {
        int base = i * 4;
        float4 v = *(const float4*)(Wh_ + base);
        f16x4 o; o[0] = (f16)v.x; o[1] = (f16)v.y; o[2] = (f16)v.z; o[3] = (f16)v.w;
        *(f16x4*)(wh + base) = o;
    }
    for (int i = i0; i < 128 * 1024 / 4; i += stride) {
        int base = i * 4;
        float4 v = *(const float4*)(Wo_ + base);
        f16x4 o; o[0] = (f16)v.x; o[1] = (f16)v.y; o[2] = (f16)v.z; o[3] = (f16)v.w;
        *(f16x4*)(wo + base) = o;
    }
}

// ---------------- init: comb = [x_0, h=0], h32 = 0, stats = 0 ----------------
__global__ void k_init(const float* __restrict__ X, f16* __restrict__ comb, float* __restrict__ h32,
                       float* __restrict__ ssum_ur, float* __restrict__ ssq_ur,
                       float* __restrict__ ssum_c, float* __restrict__ ssq_c)
{
    const int stride = gridDim.x * blockDim.x;
    const int i0 = blockIdx.x * blockDim.x + threadIdx.x;
    for (int i = i0; i < BB * DC / 4; i += stride) {
        int base = i * 4;
        int m = base / DC, k = base % DC;
        f16x4 o;
        if (k < NIN) {
            float4 v = *(const float4*)(X + (size_t)m * SS * NIN + k);  // s = 0
            o[0] = (f16)v.x; o[1] = (f16)v.y; o[2] = (f16)v.z; o[3] = (f16)v.w;
        } else {
            o[0] = (f16)0.f; o[1] = (f16)0.f; o[2] = (f16)0.f; o[3] = (f16)0.f;
        }
        *(f16x4*)(comb + base) = o;
    }
    for (int i = i0; i < BB * DH / 4; i += stride) {
        float4 z = make_float4(0.f, 0.f, 0.f, 0.f);
        *(float4*)(h32 + i * 4) = z;
    }
    for (int i = i0; i < 2 * 2048; i += stride) { ssum_ur[i] = 0.f; ssq_ur[i] = 0.f; }
    for (int i = i0; i < 2 * 1024; i += stride) { ssum_c[i] = 0.f; ssq_c[i] = 0.f; }
}

// ---------------- tiled fp16 MFMA GEMM:  C[M,N] = A[M,K] * B[N,K]^T ----------------
// 64x64 tile / WG, 4 waves (2x2), each wave 32x32 = 2x2 mfma_16x16x32 fragments.
// STATS: per-column sum/sumsq atomics (for BatchNorm).  OEPI: out = tanh(v + b_o), strided store.
template<int KT, bool STATS, bool OEPI>
__global__ __launch_bounds__(256, 1)
void k_gemm(const f16* __restrict__ A, int lda,
            const f16* __restrict__ Bm,
            float* __restrict__ C, int ldc,
            float* __restrict__ ssum, float* __restrict__ ssq,
            const float* __restrict__ bo, float* __restrict__ outp, int s)
{
    __shared__ f16 As[64][72];
    __shared__ f16 Bs[64][72];
    const int tid  = threadIdx.x;
    const int lane = tid & 63;
    const int w    = tid >> 6, wm = w >> 1, wn = w & 1;
    const int m0   = blockIdx.y * 64, n0 = blockIdx.x * 64;
    const int r0   = tid >> 3;       // staging row (0..31), +32 second half
    const int kg   = tid & 7;        // staging 8-f16 group

    const f16* Ap = A + (size_t)m0 * lda + kg * 8;
    const f16* Bp = Bm + (size_t)n0 * KT + kg * 8;

    f32x4 acc[2][2] = {};

    f16x8 pa0 = *(const f16x8*)(Ap + (size_t)r0 * lda);
    f16x8 pa1 = *(const f16x8*)(Ap + (size_t)(r0 + 32) * lda);
    f16x8 pb0 = *(const f16x8*)(Bp + (size_t)r0 * KT);
    f16x8 pb1 = *(const f16x8*)(Bp + (size_t)(r0 + 32) * KT);

    for (int kc = 0; kc < KT; kc += 64) {
        *(f16x8*)&As[r0][kg * 8]      = pa0;
        *(f16x8*)&As[r0 + 32][kg * 8] = pa1;
        *(f16x8*)&Bs[r0][kg * 8]      = pb0;
        *(f16x8*)&Bs[r0 + 32][kg * 8] = pb1;
        __syncthreads();
        if (kc + 64 < KT) {
            pa0 = *(const f16x8*)(Ap + (size_t)r0 * lda + kc + 64);
            pa1 = *(const f16x8*)(Ap + (size_t)(r0 + 32) * lda + kc + 64);
            pb0 = *(const f16x8*)(Bp + (size_t)r0 * KT + kc + 64);
            pb1 = *(const f16x8*)(Bp + (size_t)(r0 + 32) * KT + kc + 64);
        }
#pragma unroll
        for (int ks = 0; ks < 2; ++ks) {
            const int kofs = ks * 32 + (lane >> 4) * 8;
            f16x8 a0 = *(const f16x8*)&As[wm * 32 + (lane & 15)][kofs];
            f16x8 a1 = *(const f16x8*)&As[wm * 32 + 16 + (lane & 15)][kofs];
            f16x8 b0 = *(const f16x8*)&Bs[wn * 32 + (lane & 15)][kofs];
            f16x8 b1 = *(const f16x8*)&Bs[wn * 32 + 16 + (lane & 15)][kofs];
            acc[0][0] = __builtin_amdgcn_mfma_f32_16x16x32_f16(a0, b0, acc[0][0], 0, 0, 0);
            acc[0][1] = __builtin_amdgcn_mfma_f32_16x16x32_f16(a0, b1, acc[0][1], 0, 0, 0);
            acc[1][0] = __builtin_amdgcn_mfma_f32_16x16x32_f16(a1, b0, acc[1][0], 0, 0, 0);
            acc[1][1] = __builtin_amdgcn_mfma_f32_16x16x32_f16(a1, b1, acc[1][1], 0, 0, 0);
        }
        __syncthreads();
    }

#pragma unroll
    for (int fm = 0; fm < 2; ++fm) {
#pragma unroll
        for (int fn = 0; fn < 2; ++fn) {
            const int row = m0 + wm * 32 + fm * 16 + (lane >> 4) * 4;
            const int col = n0 + wn * 32 + fn * 16 + (lane & 15);
            if constexpr (OEPI) {
#pragma unroll
                for (int i = 0; i < 4; ++i) {
                    float v = tanh_(acc[fm][fn][i] + bo[col]);
                    outp[(size_t)(row + i) * (SS * NOUT) + (size_t)s * NOUT + col] = v;
                }
            } else {
#pragma unroll
                for (int i = 0; i < 4; ++i) {
                    C[(size_t)(row + i) * ldc + col] = acc[fm][fn][i];
                }
            }
        }
    }
    if constexpr (STATS) {
#pragma unroll
        for (int fn = 0; fn < 2; ++fn) {
            float s1 = 0.f, s2 = 0.f;
#pragma unroll
            for (int fm = 0; fm < 2; ++fm)
#pragma unroll
                for (int i = 0; i < 4; ++i) { float v = acc[fm][fn][i]; s1 += v; s2 += v * v; }
            s1 += __shfl_xor(s1, 16, 64); s1 += __shfl_xor(s1, 32, 64);
            s2 += __shfl_xor(s2, 16, 64); s2 += __shfl_xor(s2, 32, 64);
            if (lane < 16) {
                const int col = n0 + wn * 32 + fn * 16 + lane;
                atomicAdd(&ssum[col], s1);
                atomicAdd(&ssq[col], s2);
            }
        }
    }
}

// ---------------- gate kernel: r = sigmoid(BN(pre_r)); comb_h <- fp16(r*h) ----------------
__global__ __launch_bounds__(256)
void k_gate(const float* __restrict__ pre_ur, const float* __restrict__ h32,
            f16* __restrict__ comb,
            const float* __restrict__ ssum_ur, const float* __restrict__ ssq_ur,
            const float* __restrict__ g_r, const float* __restrict__ be_r)
{
    const int idx = blockIdx.x * 256 + threadIdx.x;   // 512*256 threads, 4 cols each
    const int m = idx >> 8, j4 = (idx & 255) << 2;
    float4 prv = *(const float4*)(pre_ur + (size_t)m * 2048 + 1024 + j4);
    float4 hv  = *(const float4*)(h32 + (size_t)m * 1024 + j4);
    float p[4] = {prv.x, prv.y, prv.z, prv.w};
    float h[4] = {hv.x, hv.y, hv.z, hv.w};
    f16x4 o;
#pragma unroll
    for (int t = 0; t < 4; ++t) {
        const int col = 1024 + j4 + t;
        float mu  = ssum_ur[col] * (1.0f / 512.0f);
        float var = fmaxf(ssq_ur[col] * (1.0f / 512.0f) - mu * mu, 0.f);
        float rq  = rsqrtf(var + EPSV);
        float r   = sigmoid_(g_r[j4 + t] * ((p[t] - mu) * rq) + be_r[j4 + t]);
        o[t] = (f16)(r * h[t]);
    }
    *(f16x4*)(comb + (size_t)m * DC + NIN + j4) = o;
}

// ---------------- update kernel: u, c, h_new; prep next step ----------------
__global__ __launch_bounds__(256)
void k_upd(const float* __restrict__ pre_ur, const float* __restrict__ pre_c,
           float* __restrict__ h32, f16* __restrict__ comb,
           const float* __restrict__ ssum_ur, const float* __restrict__ ssq_ur,
           const float* __restrict__ ssum_c, const float* __restrict__ ssq_c,
           float* __restrict__ zsum_ur, float* __restrict__ zsq_ur,
           float* __restrict__ zsum_c, float* __restrict__ zsq_c,
           const float* __restrict__ X,
           const float* __restrict__ g_u, const float* __restrict__ be_u,
           const float* __restrict__ g_h, const float* __restrict__ be_h,
           int s)
{
    const int idx = blockIdx.x * 256 + threadIdx.x;
    const int m = idx >> 8, j4 = (idx & 255) << 2;
    float4 puv = *(const float4*)(pre_ur + (size_t)m * 2048 + j4);
    float4 pcv = *(const float4*)(pre_c + (size_t)m * 1024 + j4);
    float4 hv  = *(const float4*)(h32 + (size_t)m * 1024 + j4);
    float pu[4] = {puv.x, puv.y, puv.z, puv.w};
    float pc[4] = {pcv.x, pcv.y, pcv.z, pcv.w};
    float h[4]  = {hv.x, hv.y, hv.z, hv.w};
    float hn[4];
    f16x4 o;
#pragma unroll
    for (int t = 0; t < 4; ++t) {
        const int col = j4 + t;
        float mu_u  = ssum_ur[col] * (1.0f / 512.0f);
        float var_u = fmaxf(ssq_ur[col] * (1.0f / 512.0f) - mu_u * mu_u, 0.f);
        float u = sigmoid_(g_u[col] * ((pu[t] - mu_u) * rsqrtf(var_u + EPSV)) + be_u[col]);
        float mu_c  = ssum_c[col] * (1.0f / 512.0f);
        float var_c = fmaxf(ssq_c[col] * (1.0f / 512.0f) - mu_c * mu_c, 0.f);
        float c = tanh_(g_h[col] * ((pc[t] - mu_c) * rsqrtf(var_c + EPSV)) + be_h[col]);
        float hnew = (1.f - u) * c + u * h[t];
        hn[t] = hnew; o[t] = (f16)hnew;
    }
    *(float4*)(h32 + (size_t)m * 1024 + j4) = make_float4(hn[0], hn[1], hn[2], hn[3]);
    *(f16x4*)(comb + (size_t)m * DC + NIN + j4) = o;
    if (j4 < NIN && s + 1 < SS) {
        float4 xv = *(const float4*)(X + (size_t)m * SS * NIN + (size_t)(s + 1) * NIN + j4);
        f16x4 xo; xo[0] = (f16)xv.x; xo[1] = (f16)xv.y; xo[2] = (f16)xv.z; xo[3] = (f16)xv.w;
        *(f16x4*)(comb + (size_t)m * DC + j4) = xo;
    }
    if (idx < 2048) { zsum_ur[idx] = 0.f; zsq_ur[idx] = 0.f; }
    if (idx < 1024) { zsum_c[idx] = 0.f; zsq_c[idx] = 0.f; }
}

// ---------------- host launch ----------------
extern "C" void kernel_launch(void* const* d_in, const int* in_sizes, int n_in,
                              void* d_out, int out_size, void* d_ws, size_t ws_size,
                              hipStream_t stream)
{
    const float* X    = (const float*)d_in[0];
    const float* W_u  = (const float*)d_in[1];
    const float* W_r  = (const float*)d_in[3];
    const float* W_h  = (const float*)d_in[5];
    const float* W_o  = (const float*)d_in[7];
    const float* b_o  = (const float*)d_in[8];
    const float* g_u  = (const float*)d_in[9];
    const float* be_u = (const float*)d_in[10];
    const float* g_r  = (const float*)d_in[11];
    const float* be_r = (const float*)d_in[12];
    const float* g_h  = (const float*)d_in[13];
    const float* be_h = (const float*)d_in[14];
    float* out = (float*)d_out;

    char* p = (char*)d_ws;
    auto alloc = [&](size_t bytes) { char* r = p; p += (bytes + 255) & ~(size_t)255; return r; };
    f16*   comb    = (f16*)alloc((size_t)BB * DC * 2);
    f16*   Wur     = (f16*)alloc((size_t)2048 * DC * 2);
    f16*   Wh16    = (f16*)alloc((size_t)DH * DC * 2);
    f16*   Wo16    = (f16*)alloc((size_t)NOUT * DH * 2);
    float* pre_ur  = (float*)alloc((size_t)BB * 2048 * 4);
    float* pre_c   = (float*)alloc((size_t)BB * DH * 4);
    float* h32     = (float*)alloc((size_t)BB * DH * 4);
    float* ssum_ur = (float*)alloc(2 * 2048 * 4);
    float* ssq_ur  = (float*)alloc(2 * 2048 * 4);
    float* ssum_c  = (float*)alloc(2 * 1024 * 4);
    float* ssq_c   = (float*)alloc(2 * 1024 * 4);

    k_convert<<<1024, 256, 0, stream>>>(W_u, W_r, W_h, W_o, Wur, Wh16, Wo16);
    k_init<<<1024, 256, 0, stream>>>(X, comb, h32, ssum_ur, ssq_ur, ssum_c, ssq_c);

    for (int s = 0; s < SS; ++s) {
        const int par = s & 1, nxt = 1 - par;
        // pre_ur = comb @ Wur^T  (+ column stats)
        k_gemm<DC, true, false><<<dim3(32, 8), 256, 0, stream>>>(
            comb, DC, Wur, pre_ur, 2048,
            ssum_ur + par * 2048, ssq_ur + par * 2048, nullptr, nullptr, 0);
        // r = sigmoid(BN(pre_r)); comb_h <- r*h
        k_gate<<<512, 256, 0, stream>>>(pre_ur, h32, comb,
            ssum_ur + par * 2048, ssq_ur + par * 2048, g_r, be_r);
        // pre_c = comb2 @ Wh^T (+ column stats)
        k_gemm<DC, true, false><<<dim3(16, 8), 256, 0, stream>>>(
            comb, DC, Wh16, pre_c, 1024,
            ssum_c + par * 1024, ssq_c + par * 1024, nullptr, nullptr, 0);
        // u, c, h_new; prep comb for next step; zero next-parity stats
        k_upd<<<512, 256, 0, stream>>>(pre_ur, pre_c, h32, comb,
            ssum_ur + par * 2048, ssq_ur + par * 2048,
            ssum_c + par * 1024, ssq_c + par * 1024,
            ssum_ur + nxt * 2048, ssq_ur + nxt * 2048,
            ssum_c + nxt * 1024, ssq_c + nxt * 1024,
            X, g_u, be_u, g_h, be_h, s);
        // o_s = tanh(h_new @ Wo^T + b_o)
        k_gemm<DH, false, true><<<dim3(2, 8), 256, 0, stream>>>(
            comb + NIN, DC, Wo16, nullptr, 0,
            nullptr, nullptr, b_o, out, s);
    }
}